// Round 12
// baseline (500.074 us; speedup 1.0000x reference)
//
#include <hip/hip_runtime.h>
#include <math.h>

#define TPB 256

typedef float vf4 __attribute__((ext_vector_type(4)));

__device__ __forceinline__ float gelu_f(float x) {
    return 0.5f * x * (1.0f + erff(x * 0.70710678118654752f));
}
__device__ __forceinline__ float gate_f(float x) {
    float si = x / (1.0f + expf(-x));
    return 1.0f + tanhf(si);
}

// ---- 64x64 output tile, one K-slice of split-K GEMM; X via loader functor ----
// Double-buffered: prefetch chunk i+1 (global->regs) overlaps chunk i FMAs.
// LDS: xs[32][68] k-major (store 4-way conflict only; float4 read broadcast,
// conflict-free). wt[32][68].
template <class XL>
__device__ __forceinline__ void gemm_tile(XL xload, const float* __restrict__ W, int Wld, int cb,
                                          int k0, int kslice, float* part, int totN, int gcol, int s,
                                          float* __restrict__ xs, float* __restrict__ wt)
{
    const int t = threadIdx.x;
    const int tr4 = (t >> 4) << 2;
    const int tc4 = (t & 15) << 2;
    const int a  = t >> 5, kk = t & 31;      // X staging: element (r = a+8j, k = kk)
    const int wk = t >> 6, wc = t & 63;      // W staging: element (krow = wk+4j, c = wc)
    float xv[8], wv[8];
#pragma unroll
    for (int j = 0; j < 8; ++j) {
        xv[j] = xload(a + 8 * j, k0 + kk);
        wv[j] = W[(size_t)(k0 + wk + 4 * j) * Wld + cb + wc];
    }
    float acc[4][4] = {{0.f,0.f,0.f,0.f},{0.f,0.f,0.f,0.f},{0.f,0.f,0.f,0.f},{0.f,0.f,0.f,0.f}};
    for (int kc = 0; kc < kslice; kc += 32) {
#pragma unroll
        for (int j = 0; j < 8; ++j) {
            xs[kk * 68 + a + 8 * j] = xv[j];
            wt[(wk + 4 * j) * 68 + wc] = wv[j];
        }
        __syncthreads();
        int kn = kc + 32;
        if (kn < kslice) {                   // prefetch next chunk during FMAs
#pragma unroll
            for (int j = 0; j < 8; ++j) {
                xv[j] = xload(a + 8 * j, k0 + kn + kk);
                wv[j] = W[(size_t)(k0 + kn + wk + 4 * j) * Wld + cb + wc];
            }
        }
#pragma unroll
        for (int k = 0; k < 32; ++k) {
            float4 xq = *(const float4*)&xs[k * 68 + tr4];
            float4 wq = *(const float4*)&wt[k * 68 + tc4];
            acc[0][0] += xq.x * wq.x; acc[0][1] += xq.x * wq.y; acc[0][2] += xq.x * wq.z; acc[0][3] += xq.x * wq.w;
            acc[1][0] += xq.y * wq.x; acc[1][1] += xq.y * wq.y; acc[1][2] += xq.y * wq.z; acc[1][3] += xq.y * wq.w;
            acc[2][0] += xq.z * wq.x; acc[2][1] += xq.z * wq.y; acc[2][2] += xq.z * wq.z; acc[2][3] += xq.z * wq.w;
            acc[3][0] += xq.w * wq.x; acc[3][1] += xq.w * wq.y; acc[3][2] += xq.w * wq.z; acc[3][3] += xq.w * wq.w;
        }
        __syncthreads();
    }
    float* pp = part + (size_t)(s * 64 + tr4) * totN + gcol + tc4;
#pragma unroll
    for (int i = 0; i < 4; ++i)
#pragma unroll
        for (int j = 0; j < 4; ++j)
            pp[i * totN + j] = acc[i][j];
}

#define GEMM_LDS __shared__ float xs[32 * 68]; __shared__ float wt[32 * 68];

// ---- pool1 partial task (m in 0..767): pp[(qz*64+b)*768+c] = sum over 64 q ----
__device__ __forceinline__ void pool_task(const float* __restrict__ tok_effect,
                                          float* __restrict__ pp, int m, int t)
{
    int cch = m % 3, b = (m / 3) % 64, qz = m / 192;
    int c = cch * TPB + t;
    const float* base = tok_effect + (size_t)(b * 256 + qz * 64) * 768 + c;
    float s = 0.f;
#pragma unroll 16
    for (int q = 0; q < 64; ++q) s += __builtin_nontemporal_load(base + (size_t)q * 768);
    pp[(qz * 64 + b) * 768 + c] = s;
}

// ============ K1: (cat∘g)@fuse_w1 partials (0..143) || pool 0..383 (144..527)
//              || stats1 (528..591) || 6 colvec folds (592..609) ============
struct G1Args {
    const float *ec, *ea, *flg, *flb, *w1;
    const float *dg, *db, *eg, *eb, *delta_w, *eff_w1;
    const float *tok_effect;
    float *part1, *pp, *stats1, *gW1, *bW1, *dgW, *dbW, *egW, *ebW;
};
__global__ __launch_bounds__(256) void k_g1(G1Args A)
{
    GEMM_LDS;
    __shared__ float red[8];
    const int t = threadIdx.x;
    if (blockIdx.x < 144) {
        int ct = blockIdx.x % 12, s = blockIdx.x / 12;
        auto xl = [&](int r, int k) {      // (x ∘ g): no stats needed (affine-LN trick)
            float raw = (k < 768) ? A.ec[r * 768 + k] : A.ea[r * 768 + (k - 768)];
            return raw * A.flg[k];
        };
        gemm_tile(xl, A.w1, 768, ct * 64, s * 128, 128, A.part1, 768, ct * 64, s, xs, wt);
    } else if (blockIdx.x < 528) {
        pool_task(A.tok_effect, A.pp, blockIdx.x - 144, t);
    } else if (blockIdx.x < 592) {
        // stats1 for row r: one-pass mean / rstd over concat (1536)
        int r = blockIdx.x - 528;
        float sum = 0.f, sq = 0.f;
#pragma unroll
        for (int j = 0; j < 6; ++j) {
            int c = t + j * TPB;
            float x = (c < 768) ? A.ec[r * 768 + c] : A.ea[r * 768 + (c - 768)];
            sum += x; sq += x * x;
        }
#pragma unroll
        for (int o_ = 32; o_ > 0; o_ >>= 1) { sum += __shfl_xor(sum, o_); sq += __shfl_xor(sq, o_); }
        if ((t & 63) == 0) { red[t >> 6] = sum; red[4 + (t >> 6)] = sq; }
        __syncthreads();
        if (t == 0) {
            float s = red[0] + red[1] + red[2] + red[3];
            float q = red[4] + red[5] + red[6] + red[7];
            float mean = s * (1.f / 1536.f);
            A.stats1[2 * r]     = mean;
            A.stats1[2 * r + 1] = rsqrtf(q * (1.f / 1536.f) - mean * mean + 1e-5f);
        }
    } else {
        // colvec folds: out[k] = sum_c vec[c] * W[c,k]   (N = 768 for all)
        int m = blockIdx.x - 592;
        int id = m / 3, chunk = m % 3;
        const float* vec; const float* W; int K; float* out;
        switch (id) {
            case 0: vec = A.flg; W = A.w1;      K = 1536; out = A.gW1; break;
            case 1: vec = A.flb; W = A.w1;      K = 1536; out = A.bW1; break;
            case 2: vec = A.dg;  W = A.delta_w; K = 768;  out = A.dgW; break;
            case 3: vec = A.db;  W = A.delta_w; K = 768;  out = A.dbW; break;
            case 4: vec = A.eg;  W = A.eff_w1;  K = 768;  out = A.egW; break;
            default: vec = A.eb; W = A.eff_w1;  K = 768;  out = A.ebW; break;
        }
        int col = chunk * TPB + t;
        float acc = 0.f;
        for (int c = 0; c < K; ++c) acc += vec[c] * W[(size_t)c * 768 + col];
        out[col] = acc;
    }
}

// ============ K2: h=gelu(LN-corrected fuse1) @ fuse_w2 (0..143) || pool 384..767 ============
struct G2Args {
    const float *part1, *b1, *w2, *stats1, *gW1, *bW1;
    const float *tok_effect;
    float *part2, *pp;
};
__global__ __launch_bounds__(256) void k_g2(G2Args A)
{
    GEMM_LDS;
    if (blockIdx.x >= 144) {
        pool_task(A.tok_effect, A.pp, blockIdx.x - 144 + 384, threadIdx.x);
        return;
    }
    int ct = blockIdx.x % 12, s = blockIdx.x / 12;
    auto xl = [&](int r, int k) {
        float v = 0.f;
#pragma unroll
        for (int q = 0; q < 12; ++q) v += A.part1[(size_t)(q * 64 + r) * 768 + k];
        float m = A.stats1[2 * r], rs = A.stats1[2 * r + 1];
        // LN(x)@W1 = rs*((x∘g)@W1) - rs*m*gW1 + bW1 ; then +b1, gelu
        return gelu_f(rs * (v - m * A.gW1[k]) + A.bW1[k] + A.b1[k]);
    };
    gemm_tile(xl, A.w2, 768, ct * 64, s * 64, 64, A.part2, 768, ct * 64, s, xs, wt);
}

// ============ K3: gA partials with lazy ctx (0..447) || stats2 (448..511) ============
// segments: (ctx∘dg)@delta_w | (ctx∘eg)@eff_w1 | ctx@qg_w | ctx@kg_w
struct GAArgs {
    const float *part2, *b2, *dg, *eg;
    const float *delta_w, *eff_w1, *qg_w, *kg_w;
    float *partA, *stats2;
};
__global__ __launch_bounds__(256) void k_gA(GAArgs A)
{
    GEMM_LDS;
    __shared__ float red[8];
    const int t = threadIdx.x;
    if (blockIdx.x >= 448) {
        // stats2 for ctx row r (ctx built lazily from part2)
        int r = blockIdx.x - 448;
        float sum = 0.f, sq = 0.f;
#pragma unroll
        for (int j = 0; j < 3; ++j) {
            int c = t + j * TPB;
            float x = A.b2[c];
#pragma unroll
            for (int q = 0; q < 12; ++q) x += A.part2[(size_t)(q * 64 + r) * 768 + c];
            sum += x; sq += x * x;
        }
#pragma unroll
        for (int o_ = 32; o_ > 0; o_ >>= 1) { sum += __shfl_xor(sum, o_); sq += __shfl_xor(sq, o_); }
        if ((t & 63) == 0) { red[t >> 6] = sum; red[4 + (t >> 6)] = sq; }
        __syncthreads();
        if (t == 0) {
            float s = red[0] + red[1] + red[2] + red[3];
            float q = red[4] + red[5] + red[6] + red[7];
            float mean = s * (1.f / 768.f);
            A.stats2[2 * r]     = mean;
            A.stats2[2 * r + 1] = rsqrtf(q * (1.f / 768.f) - mean * mean + 1e-5f);
        }
        return;
    }
    int ct = blockIdx.x % 56, s = blockIdx.x / 56;
    auto ctxv = [&](int r, int k) {
        float v = A.b2[k];
#pragma unroll
        for (int q = 0; q < 12; ++q) v += A.part2[(size_t)(q * 64 + r) * 768 + k];
        return v;
    };
    if (ct < 12) {
        auto xl = [&](int r, int k) { return ctxv(r, k) * A.dg[k]; };
        gemm_tile(xl, A.delta_w, 768, ct * 64, s * 96, 96, A.partA, 3584, ct * 64, s, xs, wt);
    } else if (ct < 24) {
        auto xl = [&](int r, int k) { return ctxv(r, k) * A.eg[k]; };
        gemm_tile(xl, A.eff_w1, 768, (ct - 12) * 64, s * 96, 96, A.partA, 3584, ct * 64, s, xs, wt);
    } else {
        auto xl = [&](int r, int k) { return ctxv(r, k); };
        const float* W = (ct < 40) ? A.qg_w : A.kg_w;
        int cb = (ct < 40) ? (ct - 24) * 64 : (ct - 40) * 64;
        gemm_tile(xl, W, 1024, cb, s * 96, 96, A.partA, 3584, ct * 64, s, xs, wt);
    }
}

// ============ K4 mid: batchA outputs (0..27) || batchB partials (28..251) ============
struct MidArgs {
    const float *partA, *pp, *stats2, *dgW, *dbW, *egW, *ebW;
    const float *delta_b, *eff_b1, *qg_b, *kg_b, *eff_w2, *u_w;
    float *partB, *out_de, *out_es, *out_qg, *out_kg;
};
__global__ __launch_bounds__(256) void k_mid(MidArgs A)
{
    GEMM_LDS;
    const int t = threadIdx.x;
    if (blockIdx.x < 28) {
#pragma unroll
        for (int ii = 0; ii < 32; ++ii) {
            int idx = blockIdx.x * TPB + t + ii * 7168;     // 64*3584 = 28*256*32
            int r = idx / 3584, c = idx - r * 3584;
            if (c >= 768 && c < 1536) continue;             // eff1: consumed lazily
            float v = 0.f;
#pragma unroll
            for (int q = 0; q < 8; ++q) v += A.partA[(size_t)(q * 64 + r) * 3584 + c];
            if (c < 768) {
                float m = A.stats2[2 * r], rs = A.stats2[2 * r + 1];
                float de = rs * (v - m * A.dgW[c]) + A.dbW[c] + A.delta_b[c];
                A.out_de[r * 768 + c] = de;
                float s4 = A.pp[r * 768 + c] + A.pp[(64 + r) * 768 + c]
                         + A.pp[(128 + r) * 768 + c] + A.pp[(192 + r) * 768 + c];
                A.out_es[r * 768 + c] = de + s4 * (1.f / 256.f);
            } else if (c < 2560) {
                A.out_qg[r * 1024 + (c - 1536)] = gate_f(v + A.qg_b[c - 1536]);
            } else {
                A.out_kg[r * 1024 + (c - 2560)] = gate_f(v + A.kg_b[c - 2560]);
            }
        }
    } else {
        int m = blockIdx.x - 28;              // 0..223
        int ct = m % 28, s = m / 28;          // 8 slices, kslice=96
        if (ct < 12) {
            auto xl = [&](int r, int k) {     // eh = gelu(LN-corrected eff1), lazily
                float v = 0.f;
#pragma unroll
                for (int q = 0; q < 8; ++q) v += A.partA[(size_t)(q * 64 + r) * 3584 + 768 + k];
                float mm = A.stats2[2 * r], rs = A.stats2[2 * r + 1];
                return gelu_f(rs * (v - mm * A.egW[k]) + A.ebW[k] + A.eff_b1[k]);
            };
            gemm_tile(xl, A.eff_w2, 768, ct * 64, s * 96, 96, A.partB, 1792, ct * 64, s, xs, wt);
        } else {
            auto xl = [&](int r, int k) {     // e_shifted = delta_e + pooled, lazily
                float v = 0.f;
#pragma unroll
                for (int q = 0; q < 8; ++q) v += A.partA[(size_t)(q * 64 + r) * 3584 + k];
                float mm = A.stats2[2 * r], rs = A.stats2[2 * r + 1];
                float de = rs * (v - mm * A.dgW[k]) + A.dbW[k] + A.delta_b[k];
                float s4 = A.pp[r * 768 + k] + A.pp[(64 + r) * 768 + k]
                         + A.pp[(128 + r) * 768 + k] + A.pp[(192 + r) * 768 + k];
                return de + s4 * (1.f / 256.f);
            };
            gemm_tile(xl, A.u_w, 1024, (ct - 12) * 64, s * 96, 96, A.partB, 1792, ct * 64, s, xs, wt);
        }
    }
}

// ============ K5 tail: effect_pred epilogue (0..5) || wu (6..101) ============
__global__ __launch_bounds__(256) void k_tail(const float* __restrict__ partB, const float* __restrict__ eff_b2,
                                              const float* __restrict__ v_w,
                                              float* __restrict__ out_ep, float* __restrict__ wu)
{
    const int t = threadIdx.x;
    if (blockIdx.x < 6) {
#pragma unroll
        for (int ii = 0; ii < 32; ++ii) {
            int idx = blockIdx.x * TPB + t + ii * 1536;    // 64*768 = 6*256*32
            int r = idx / 768, c = idx - r * 768;
            float v = eff_b2[c];
#pragma unroll
            for (int q = 0; q < 8; ++q) v += partB[(size_t)(q * 64 + r) * 1792 + c];
            out_ep[r * 768 + c] = v;
        }
    } else {
        __shared__ float us[64 * 132];
        int m = blockIdx.x - 6;                 // 0..95
        int h = m / 12, ctile = m % 12;
        for (int n = t; n < 8192; n += TPB) {
            int b = n >> 7, d = n & 127;
            float v = 0.f;
#pragma unroll
            for (int q = 0; q < 8; ++q) v += partB[(size_t)(q * 64 + b) * 1792 + 768 + h * 128 + d];
            us[b * 132 + d] = v;                // u[b, h*128+d]
        }
        __syncthreads();
        int c = ctile * 64 + (t >> 2);
        int bo = t & 3;
        const float* vr = v_w + (size_t)c * 1024 + h * 128;
        float acc[16];
#pragma unroll
        for (int i = 0; i < 16; ++i) acc[i] = 0.f;
        for (int d = 0; d < 128; d += 4) {
            float4 w4 = *(const float4*)(vr + d);
#pragma unroll
            for (int i = 0; i < 16; ++i) {
                const float* ub = &us[(4 * i + bo) * 132 + d];
                acc[i] += w4.x * ub[0] + w4.y * ub[1] + w4.z * ub[2] + w4.w * ub[3];
            }
        }
#pragma unroll
        for (int i = 0; i < 16; ++i) {
            int b = 4 * i + bo;
            wu[(b * 8 + h) * 768 + c] = acc[i];
        }
    }
}

// ============ K6: fused bias + broadcast (512 threads) ============
__global__ __launch_bounds__(512) void k_biasbc(const float* __restrict__ tok_cause, const float* __restrict__ wu,
                         const float* __restrict__ ls_ptr, float* __restrict__ out_lb)
{
    int b = blockIdx.x, kt = blockIdx.y;
    __shared__ float wuh[8 * 768];     // 24 KB
    __shared__ float bsm[8 * 32];      // bias values [h][k_local]
    for (int n = threadIdx.x; n < 6144; n += 512)
        wuh[n] = wu[b * 6144 + n];
    __syncthreads();
    const int lane = threadIdx.x & 63, w = threadIdx.x >> 6;   // 8 waves
    vf4 wur[3][8];
#pragma unroll
    for (int j = 0; j < 3; ++j)
#pragma unroll
        for (int h = 0; h < 8; ++h)
            wur[j][h] = *(const vf4*)&wuh[h * 768 + (lane + 64 * j) * 4];
    float scale = expf(ls_ptr[0]) * 0.08838834764831845f;
#pragma unroll
    for (int rr = 0; rr < 4; ++rr) {
        int rl = w * 4 + rr;                    // 0..31 local k-row
        int row = kt * 32 + rl;
        const vf4* tr = (const vf4*)(tok_cause + ((size_t)b * 256 + row) * 768);
        vf4 t0 = tr[lane];
        vf4 t1 = tr[lane + 64];
        vf4 t2 = tr[lane + 128];
        float acc[8];
#pragma unroll
        for (int h = 0; h < 8; ++h) {
            acc[h] = t0.x * wur[0][h].x + t0.y * wur[0][h].y + t0.z * wur[0][h].z + t0.w * wur[0][h].w
                   + t1.x * wur[1][h].x + t1.y * wur[1][h].y + t1.z * wur[1][h].z + t1.w * wur[1][h].w
                   + t2.x * wur[2][h].x + t2.y * wur[2][h].y + t2.z * wur[2][h].z + t2.w * wur[2][h].w;
        }
#pragma unroll
        for (int h = 0; h < 8; ++h) {
            float vv = acc[h];
#pragma unroll
            for (int o_ = 32; o_ > 0; o_ >>= 1) vv += __shfl_xor(vv, o_);
            if (lane == 0) bsm[h * 32 + rl] = vv * scale;
        }
    }
    __syncthreads();
    const vf4* bs4 = (const vf4*)bsm;          // [8][8]
    vf4* o4 = (vf4*)out_lb;
    int v = threadIdx.x & 7, sq0 = threadIdx.x >> 3;   // 64 segments per pass
#pragma unroll
    for (int it = 0; it < 32; ++it) {
        int seg = sq0 + it * 64;               // 0..2047 = h*256 + q
        int h = seg >> 8, q = seg & 255;
        vf4 val = bs4[h * 8 + v];
        __builtin_nontemporal_store(val, &o4[(((size_t)(b * 8 + h) * 256 + q) << 6) + kt * 8 + v]);
    }
}

extern "C" void kernel_launch(void* const* d_in, const int* in_sizes, int n_in,
                              void* d_out, int out_size, void* d_ws, size_t ws_size,
                              hipStream_t stream)
{
    (void)in_sizes; (void)n_in; (void)out_size; (void)ws_size;
    const float* emb_cause  = (const float*)d_in[0];
    const float* emb_action = (const float*)d_in[1];
    const float* tok_cause  = (const float*)d_in[2];
    const float* tok_effect = (const float*)d_in[3];
    const float* fuse_ln_g  = (const float*)d_in[4];
    const float* fuse_ln_b  = (const float*)d_in[5];
    const float* fuse_w1    = (const float*)d_in[6];
    const float* fuse_b1    = (const float*)d_in[7];
    const float* fuse_w2    = (const float*)d_in[8];
    const float* fuse_b2    = (const float*)d_in[9];
    const float* delta_ln_g = (const float*)d_in[10];
    const float* delta_ln_b = (const float*)d_in[11];
    const float* delta_w    = (const float*)d_in[12];
    const float* delta_b    = (const float*)d_in[13];
    const float* qg_w       = (const float*)d_in[14];
    const float* qg_b       = (const float*)d_in[15];
    const float* kg_w       = (const float*)d_in[16];
    const float* kg_b       = (const float*)d_in[17];
    const float* eff_ln_g   = (const float*)d_in[18];
    const float* eff_ln_b   = (const float*)d_in[19];
    const float* eff_w1     = (const float*)d_in[20];
    const float* eff_b1     = (const float*)d_in[21];
    const float* eff_w2     = (const float*)d_in[22];
    const float* eff_b2     = (const float*)d_in[23];
    const float* u_w        = (const float*)d_in[24];
    const float* v_w        = (const float*)d_in[25];
    const float* logit_sc   = (const float*)d_in[26];

    float* ws = (float*)d_ws;
    float* pp     = ws + 0;        // 196608
    float* wu     = ws + 196608;   // 393216
    float* stats1 = ws + 589824;   // 128
    float* stats2 = ws + 589952;   // 128
    float* gW1    = ws + 590080;   // 768
    float* bW1    = ws + 590848;   // 768
    float* dgW    = ws + 591616;   // 768
    float* dbW    = ws + 592384;   // 768
    float* egW    = ws + 593152;   // 768
    float* ebW    = ws + 593920;   // 768  (end 594688 floats = 2.4 MB)

    float* out    = (float*)d_out;
    float* out_qg = out + 0;
    float* out_kg = out + 65536;
    float* out_es = out + 131072;
    float* out_de = out + 180224;
    float* out_lb = out + 229376;
    float* out_ep = out + 33783808;

    // split-K partial buffers in the tail of logit_bias (overwritten last by k_biasbc)
    float* pbase = out_lb + 20000000;
    float* part1 = pbase;             // 12*64*768 = 589824
    float* part2 = pbase + 589824;    // 12*64*768 = 589824
    float* partA = pbase + 1179648;   //  8*64*3584 = 1835008
    float* partB = pbase + 3014656;   //  8*64*1792 = 917504 (end 3.93M < 13.3M spare)

    // K1: statless fuse1 GEMM || pool 0-383 || stats1 || colvec folds
    {
        G1Args A; A.ec = emb_cause; A.ea = emb_action;
        A.flg = fuse_ln_g; A.flb = fuse_ln_b; A.w1 = fuse_w1;
        A.dg = delta_ln_g; A.db = delta_ln_b; A.eg = eff_ln_g; A.eb = eff_ln_b;
        A.delta_w = delta_w; A.eff_w1 = eff_w1;
        A.tok_effect = tok_effect;
        A.part1 = part1; A.pp = pp; A.stats1 = stats1;
        A.gW1 = gW1; A.bW1 = bW1; A.dgW = dgW; A.dbW = dbW; A.egW = egW; A.ebW = ebW;
        k_g1<<<610, TPB, 0, stream>>>(A);
    }
    // K2: fuse2 GEMM (lazy LN-corrected GELU loader) || pool 384-767
    {
        G2Args A; A.part1 = part1; A.b1 = fuse_b1; A.w2 = fuse_w2;
        A.stats1 = stats1; A.gW1 = gW1; A.bW1 = bW1;
        A.tok_effect = tok_effect; A.part2 = part2; A.pp = pp;
        k_g2<<<528, TPB, 0, stream>>>(A);
    }
    // K3: batchA partials (lazy ctx, statless) || stats2
    {
        GAArgs A; A.part2 = part2; A.b2 = fuse_b2;
        A.dg = delta_ln_g; A.eg = eff_ln_g;
        A.delta_w = delta_w; A.eff_w1 = eff_w1; A.qg_w = qg_w; A.kg_w = kg_w;
        A.partA = partA; A.stats2 = stats2;
        k_gA<<<512, TPB, 0, stream>>>(A);
    }
    // K4: batchA outputs (affine-corrected) || batchB partials
    {
        MidArgs M; M.partA = partA; M.pp = pp; M.stats2 = stats2;
        M.dgW = dgW; M.dbW = dbW; M.egW = egW; M.ebW = ebW;
        M.delta_b = delta_b; M.eff_b1 = eff_b1; M.qg_b = qg_b; M.kg_b = kg_b;
        M.eff_w2 = eff_w2; M.u_w = u_w; M.partB = partB;
        M.out_de = out_de; M.out_es = out_es; M.out_qg = out_qg; M.out_kg = out_kg;
        k_mid<<<252, TPB, 0, stream>>>(M);
    }
    // K5: effect_pred epilogue || wu fold
    k_tail<<<102, TPB, 0, stream>>>(partB, eff_b2, v_w, out_ep, wu);
    // K6: fused per-(b,h,k) bias + q-broadcast
    k_biasbc<<<dim3(64, 8), 512, 0, stream>>>(tok_cause, wu, logit_sc, out_lb);
}

// Round 13
// 142.725 us; speedup vs baseline: 3.5038x; 3.5038x over previous
//
#include <hip/hip_runtime.h>
#include <math.h>

#define TPB 256

typedef float vf4 __attribute__((ext_vector_type(4)));

__device__ __forceinline__ float gelu_f(float x) {
    return 0.5f * x * (1.0f + erff(x * 0.70710678118654752f));
}
__device__ __forceinline__ float gate_f(float x) {
    float si = x / (1.0f + expf(-x));
    return 1.0f + tanhf(si);
}

// ---- 64x64 output tile, one K-slice of split-K GEMM; X via loader functor ----
template <class XL>
__device__ __forceinline__ void gemm_tile(XL xload, const float* __restrict__ W, int Wld, int cb,
                                          int k0, int kslice, float* part, int totN, int gcol, int s,
                                          float* __restrict__ xs, float* __restrict__ wt)
{
    const int t = threadIdx.x;
    const int tr4 = (t >> 4) << 2;
    const int tc4 = (t & 15) << 2;
    const int a  = t >> 5, kk = t & 31;      // X staging: element (r = a+8j, k = kk)
    const int wk = t >> 6, wc = t & 63;      // W staging: element (krow = wk+4j, c = wc)
    float xv[8], wv[8];
#pragma unroll
    for (int j = 0; j < 8; ++j) {
        xv[j] = xload(a + 8 * j, k0 + kk);
        wv[j] = W[(size_t)(k0 + wk + 4 * j) * Wld + cb + wc];
    }
    float acc[4][4] = {{0.f,0.f,0.f,0.f},{0.f,0.f,0.f,0.f},{0.f,0.f,0.f,0.f},{0.f,0.f,0.f,0.f}};
    for (int kc = 0; kc < kslice; kc += 32) {
#pragma unroll
        for (int j = 0; j < 8; ++j) {
            xs[kk * 68 + a + 8 * j] = xv[j];
            wt[(wk + 4 * j) * 68 + wc] = wv[j];
        }
        __syncthreads();
        int kn = kc + 32;
        if (kn < kslice) {                   // prefetch next chunk during FMAs
#pragma unroll
            for (int j = 0; j < 8; ++j) {
                xv[j] = xload(a + 8 * j, k0 + kn + kk);
                wv[j] = W[(size_t)(k0 + kn + wk + 4 * j) * Wld + cb + wc];
            }
        }
#pragma unroll
        for (int k = 0; k < 32; ++k) {
            float4 xq = *(const float4*)&xs[k * 68 + tr4];
            float4 wq = *(const float4*)&wt[k * 68 + tc4];
            acc[0][0] += xq.x * wq.x; acc[0][1] += xq.x * wq.y; acc[0][2] += xq.x * wq.z; acc[0][3] += xq.x * wq.w;
            acc[1][0] += xq.y * wq.x; acc[1][1] += xq.y * wq.y; acc[1][2] += xq.y * wq.z; acc[1][3] += xq.y * wq.w;
            acc[2][0] += xq.z * wq.x; acc[2][1] += xq.z * wq.y; acc[2][2] += xq.z * wq.z; acc[2][3] += xq.z * wq.w;
            acc[3][0] += xq.w * wq.x; acc[3][1] += xq.w * wq.y; acc[3][2] += xq.w * wq.z; acc[3][3] += xq.w * wq.w;
        }
        __syncthreads();
    }
    float* pp = part + (size_t)(s * 64 + tr4) * totN + gcol + tc4;
#pragma unroll
    for (int i = 0; i < 4; ++i)
#pragma unroll
        for (int j = 0; j < 4; ++j)
            pp[i * totN + j] = acc[i][j];
}

#define GEMM_LDS __shared__ float xs[32 * 68]; __shared__ float wt[32 * 68];

// ---- pool1 partial task (m in 0..767): pp[(qz*64+b)*768+c] = sum over 64 q ----
__device__ __forceinline__ void pool_task(const float* __restrict__ tok_effect,
                                          float* __restrict__ pp, int m, int t)
{
    int cch = m % 3, b = (m / 3) % 64, qz = m / 192;
    int c = cch * TPB + t;
    const float* base = tok_effect + (size_t)(b * 256 + qz * 64) * 768 + c;
    float s = 0.f;
#pragma unroll 16
    for (int q = 0; q < 64; ++q) s += __builtin_nontemporal_load(base + (size_t)q * 768);
    pp[(qz * 64 + b) * 768 + c] = s;
}

// ============ K1: (cat∘g)@fuse_w1 partials (0..143) || pool 0..383 (144..527)
//              || stats1 (528..591) || 6 colvec folds x 12 chunks (592..663) ============
struct G1Args {
    const float *ec, *ea, *flg, *flb, *w1;
    const float *dg, *db, *eg, *eb, *delta_w, *eff_w1;
    const float *tok_effect;
    float *part1, *pp, *stats1, *gW1, *bW1, *dgW, *dbW, *egW, *ebW;
};
__global__ __launch_bounds__(256) void k_g1(G1Args A)
{
    GEMM_LDS;
    __shared__ float red[8];
    const int t = threadIdx.x;
    if (blockIdx.x < 144) {
        int ct = blockIdx.x % 12, s = blockIdx.x / 12;
        auto xl = [&](int r, int k) {      // (x ∘ g): no stats needed (affine-LN trick)
            float raw = (k < 768) ? A.ec[r * 768 + k] : A.ea[r * 768 + (k - 768)];
            return raw * A.flg[k];
        };
        gemm_tile(xl, A.w1, 768, ct * 64, s * 128, 128, A.part1, 768, ct * 64, s, xs, wt);
    } else if (blockIdx.x < 528) {
        pool_task(A.tok_effect, A.pp, blockIdx.x - 144, t);
    } else if (blockIdx.x < 592) {
        // stats1 for row r: one-pass mean / rstd over concat (1536)
        int r = blockIdx.x - 528;
        float sum = 0.f, sq = 0.f;
#pragma unroll
        for (int j = 0; j < 6; ++j) {
            int c = t + j * TPB;
            float x = (c < 768) ? A.ec[r * 768 + c] : A.ea[r * 768 + (c - 768)];
            sum += x; sq += x * x;
        }
#pragma unroll
        for (int o_ = 32; o_ > 0; o_ >>= 1) { sum += __shfl_xor(sum, o_); sq += __shfl_xor(sq, o_); }
        if ((t & 63) == 0) { red[t >> 6] = sum; red[4 + (t >> 6)] = sq; }
        __syncthreads();
        if (t == 0) {
            float s = red[0] + red[1] + red[2] + red[3];
            float q = red[4] + red[5] + red[6] + red[7];
            float mean = s * (1.f / 1536.f);
            A.stats1[2 * r]     = mean;
            A.stats1[2 * r + 1] = rsqrtf(q * (1.f / 1536.f) - mean * mean + 1e-5f);
        }
    } else {
        // colvec folds: out[col] = sum_c vec[c] * W[c,col]; 6 folds x 12 chunks of 64 cols.
        // 4 c-stripes/column + unroll 16 => 16 loads in flight (round-12 bug: 1 per iter).
        int m = blockIdx.x - 592;          // 0..71
        int id = m / 12, chunk = m % 12;
        const float* vec; const float* W; int K; float* out;
        switch (id) {
            case 0: vec = A.flg; W = A.w1;      K = 1536; out = A.gW1; break;
            case 1: vec = A.flb; W = A.w1;      K = 1536; out = A.bW1; break;
            case 2: vec = A.dg;  W = A.delta_w; K = 768;  out = A.dgW; break;
            case 3: vec = A.db;  W = A.delta_w; K = 768;  out = A.dbW; break;
            case 4: vec = A.eg;  W = A.eff_w1;  K = 768;  out = A.egW; break;
            default: vec = A.eb; W = A.eff_w1;  K = 768;  out = A.ebW; break;
        }
        int col = chunk * 64 + (t & 63);
        int stripe = t >> 6;               // 0..3
        float acc = 0.f;
#pragma unroll 16
        for (int c = stripe; c < K; c += 4)
            acc += vec[c] * W[(size_t)c * 768 + col];
        xs[stripe * 64 + (t & 63)] = acc;  // reuse GEMM LDS for the 4-way reduce
        __syncthreads();
        if (t < 64)
            out[chunk * 64 + t] = xs[t] + xs[64 + t] + xs[128 + t] + xs[192 + t];
    }
}

// ============ K2: h=gelu(LN-corrected fuse1) @ fuse_w2 (0..143) || pool 384..767 ============
struct G2Args {
    const float *part1, *b1, *w2, *stats1, *gW1, *bW1;
    const float *tok_effect;
    float *part2, *pp;
};
__global__ __launch_bounds__(256) void k_g2(G2Args A)
{
    GEMM_LDS;
    if (blockIdx.x >= 144) {
        pool_task(A.tok_effect, A.pp, blockIdx.x - 144 + 384, threadIdx.x);
        return;
    }
    int ct = blockIdx.x % 12, s = blockIdx.x / 12;
    auto xl = [&](int r, int k) {
        float v = 0.f;
#pragma unroll
        for (int q = 0; q < 12; ++q) v += A.part1[(size_t)(q * 64 + r) * 768 + k];
        float m = A.stats1[2 * r], rs = A.stats1[2 * r + 1];
        // LN(x)@W1 = rs*((x∘g)@W1) - rs*m*gW1 + bW1 ; then +b1, gelu
        return gelu_f(rs * (v - m * A.gW1[k]) + A.bW1[k] + A.b1[k]);
    };
    gemm_tile(xl, A.w2, 768, ct * 64, s * 64, 64, A.part2, 768, ct * 64, s, xs, wt);
}

// ============ K3: gA partials with lazy ctx (0..447) || stats2 (448..511) ============
struct GAArgs {
    const float *part2, *b2, *dg, *eg;
    const float *delta_w, *eff_w1, *qg_w, *kg_w;
    float *partA, *stats2;
};
__global__ __launch_bounds__(256) void k_gA(GAArgs A)
{
    GEMM_LDS;
    __shared__ float red[8];
    const int t = threadIdx.x;
    if (blockIdx.x >= 448) {
        // stats2 for ctx row r (ctx built lazily from part2)
        int r = blockIdx.x - 448;
        float sum = 0.f, sq = 0.f;
#pragma unroll
        for (int j = 0; j < 3; ++j) {
            int c = t + j * TPB;
            float x = A.b2[c];
#pragma unroll
            for (int q = 0; q < 12; ++q) x += A.part2[(size_t)(q * 64 + r) * 768 + c];
            sum += x; sq += x * x;
        }
#pragma unroll
        for (int o_ = 32; o_ > 0; o_ >>= 1) { sum += __shfl_xor(sum, o_); sq += __shfl_xor(sq, o_); }
        if ((t & 63) == 0) { red[t >> 6] = sum; red[4 + (t >> 6)] = sq; }
        __syncthreads();
        if (t == 0) {
            float s = red[0] + red[1] + red[2] + red[3];
            float q = red[4] + red[5] + red[6] + red[7];
            float mean = s * (1.f / 768.f);
            A.stats2[2 * r]     = mean;
            A.stats2[2 * r + 1] = rsqrtf(q * (1.f / 768.f) - mean * mean + 1e-5f);
        }
        return;
    }
    int ct = blockIdx.x % 56, s = blockIdx.x / 56;
    auto ctxv = [&](int r, int k) {
        float v = A.b2[k];
#pragma unroll
        for (int q = 0; q < 12; ++q) v += A.part2[(size_t)(q * 64 + r) * 768 + k];
        return v;
    };
    if (ct < 12) {
        auto xl = [&](int r, int k) { return ctxv(r, k) * A.dg[k]; };
        gemm_tile(xl, A.delta_w, 768, ct * 64, s * 96, 96, A.partA, 3584, ct * 64, s, xs, wt);
    } else if (ct < 24) {
        auto xl = [&](int r, int k) { return ctxv(r, k) * A.eg[k]; };
        gemm_tile(xl, A.eff_w1, 768, (ct - 12) * 64, s * 96, 96, A.partA, 3584, ct * 64, s, xs, wt);
    } else {
        auto xl = [&](int r, int k) { return ctxv(r, k); };
        const float* W = (ct < 40) ? A.qg_w : A.kg_w;
        int cb = (ct < 40) ? (ct - 24) * 64 : (ct - 40) * 64;
        gemm_tile(xl, W, 1024, cb, s * 96, 96, A.partA, 3584, ct * 64, s, xs, wt);
    }
}

// ============ K4 mid: batchA outputs (0..27) || batchB partials (28..251) ============
struct MidArgs {
    const float *partA, *pp, *stats2, *dgW, *dbW, *egW, *ebW;
    const float *delta_b, *eff_b1, *qg_b, *kg_b, *eff_w2, *u_w;
    float *partB, *out_de, *out_es, *out_qg, *out_kg;
};
__global__ __launch_bounds__(256) void k_mid(MidArgs A)
{
    GEMM_LDS;
    const int t = threadIdx.x;
    if (blockIdx.x < 28) {
#pragma unroll
        for (int ii = 0; ii < 32; ++ii) {
            int idx = blockIdx.x * TPB + t + ii * 7168;     // 64*3584 = 28*256*32
            int r = idx / 3584, c = idx - r * 3584;
            if (c >= 768 && c < 1536) continue;             // eff1: consumed lazily
            float v = 0.f;
#pragma unroll
            for (int q = 0; q < 8; ++q) v += A.partA[(size_t)(q * 64 + r) * 3584 + c];
            if (c < 768) {
                float m = A.stats2[2 * r], rs = A.stats2[2 * r + 1];
                float de = rs * (v - m * A.dgW[c]) + A.dbW[c] + A.delta_b[c];
                A.out_de[r * 768 + c] = de;
                float s4 = A.pp[r * 768 + c] + A.pp[(64 + r) * 768 + c]
                         + A.pp[(128 + r) * 768 + c] + A.pp[(192 + r) * 768 + c];
                A.out_es[r * 768 + c] = de + s4 * (1.f / 256.f);
            } else if (c < 2560) {
                A.out_qg[r * 1024 + (c - 1536)] = gate_f(v + A.qg_b[c - 1536]);
            } else {
                A.out_kg[r * 1024 + (c - 2560)] = gate_f(v + A.kg_b[c - 2560]);
            }
        }
    } else {
        int m = blockIdx.x - 28;              // 0..223
        int ct = m % 28, s = m / 28;          // 8 slices, kslice=96
        if (ct < 12) {
            auto xl = [&](int r, int k) {     // eh = gelu(LN-corrected eff1), lazily
                float v = 0.f;
#pragma unroll
                for (int q = 0; q < 8; ++q) v += A.partA[(size_t)(q * 64 + r) * 3584 + 768 + k];
                float mm = A.stats2[2 * r], rs = A.stats2[2 * r + 1];
                return gelu_f(rs * (v - mm * A.egW[k]) + A.ebW[k] + A.eff_b1[k]);
            };
            gemm_tile(xl, A.eff_w2, 768, ct * 64, s * 96, 96, A.partB, 1792, ct * 64, s, xs, wt);
        } else {
            auto xl = [&](int r, int k) {     // e_shifted = delta_e + pooled, lazily
                float v = 0.f;
#pragma unroll
                for (int q = 0; q < 8; ++q) v += A.partA[(size_t)(q * 64 + r) * 3584 + k];
                float mm = A.stats2[2 * r], rs = A.stats2[2 * r + 1];
                float de = rs * (v - mm * A.dgW[k]) + A.dbW[k] + A.delta_b[k];
                float s4 = A.pp[r * 768 + k] + A.pp[(64 + r) * 768 + k]
                         + A.pp[(128 + r) * 768 + k] + A.pp[(192 + r) * 768 + k];
                return de + s4 * (1.f / 256.f);
            };
            gemm_tile(xl, A.u_w, 1024, (ct - 12) * 64, s * 96, 96, A.partB, 1792, ct * 64, s, xs, wt);
        }
    }
}

// ============ K5 tail: effect_pred epilogue (0..5) || wu (6..101) ============
__global__ __launch_bounds__(256) void k_tail(const float* __restrict__ partB, const float* __restrict__ eff_b2,
                                              const float* __restrict__ v_w,
                                              float* __restrict__ out_ep, float* __restrict__ wu)
{
    const int t = threadIdx.x;
    if (blockIdx.x < 6) {
#pragma unroll
        for (int ii = 0; ii < 32; ++ii) {
            int idx = blockIdx.x * TPB + t + ii * 1536;    // 64*768 = 6*256*32
            int r = idx / 768, c = idx - r * 768;
            float v = eff_b2[c];
#pragma unroll
            for (int q = 0; q < 8; ++q) v += partB[(size_t)(q * 64 + r) * 1792 + c];
            out_ep[r * 768 + c] = v;
        }
    } else {
        __shared__ float us[64 * 132];
        int m = blockIdx.x - 6;                 // 0..95
        int h = m / 12, ctile = m % 12;
        for (int n = t; n < 8192; n += TPB) {
            int b = n >> 7, d = n & 127;
            float v = 0.f;
#pragma unroll
            for (int q = 0; q < 8; ++q) v += partB[(size_t)(q * 64 + b) * 1792 + 768 + h * 128 + d];
            us[b * 132 + d] = v;                // u[b, h*128+d]
        }
        __syncthreads();
        int c = ctile * 64 + (t >> 2);
        int bo = t & 3;
        const float* vr = v_w + (size_t)c * 1024 + h * 128;
        float acc[16];
#pragma unroll
        for (int i = 0; i < 16; ++i) acc[i] = 0.f;
        for (int d = 0; d < 128; d += 4) {
            float4 w4 = *(const float4*)(vr + d);
#pragma unroll
            for (int i = 0; i < 16; ++i) {
                const float* ub = &us[(4 * i + bo) * 132 + d];
                acc[i] += w4.x * ub[0] + w4.y * ub[1] + w4.z * ub[2] + w4.w * ub[3];
            }
        }
#pragma unroll
        for (int i = 0; i < 16; ++i) {
            int b = 4 * i + bo;
            wu[(b * 8 + h) * 768 + c] = acc[i];
        }
    }
}

// ============ K6: fused bias + broadcast (512 threads) ============
__global__ __launch_bounds__(512) void k_biasbc(const float* __restrict__ tok_cause, const float* __restrict__ wu,
                         const float* __restrict__ ls_ptr, float* __restrict__ out_lb)
{
    int b = blockIdx.x, kt = blockIdx.y;
    __shared__ float wuh[8 * 768];     // 24 KB
    __shared__ float bsm[8 * 32];      // bias values [h][k_local]
    for (int n = threadIdx.x; n < 6144; n += 512)
        wuh[n] = wu[b * 6144 + n];
    __syncthreads();
    const int lane = threadIdx.x & 63, w = threadIdx.x >> 6;   // 8 waves
    vf4 wur[3][8];
#pragma unroll
    for (int j = 0; j < 3; ++j)
#pragma unroll
        for (int h = 0; h < 8; ++h)
            wur[j][h] = *(const vf4*)&wuh[h * 768 + (lane + 64 * j) * 4];
    float scale = expf(ls_ptr[0]) * 0.08838834764831845f;
#pragma unroll
    for (int rr = 0; rr < 4; ++rr) {
        int rl = w * 4 + rr;                    // 0..31 local k-row
        int row = kt * 32 + rl;
        const vf4* tr = (const vf4*)(tok_cause + ((size_t)b * 256 + row) * 768);
        vf4 t0 = tr[lane];
        vf4 t1 = tr[lane + 64];
        vf4 t2 = tr[lane + 128];
        float acc[8];
#pragma unroll
        for (int h = 0; h < 8; ++h) {
            acc[h] = t0.x * wur[0][h].x + t0.y * wur[0][h].y + t0.z * wur[0][h].z + t0.w * wur[0][h].w
                   + t1.x * wur[1][h].x + t1.y * wur[1][h].y + t1.z * wur[1][h].z + t1.w * wur[1][h].w
                   + t2.x * wur[2][h].x + t2.y * wur[2][h].y + t2.z * wur[2][h].z + t2.w * wur[2][h].w;
        }
#pragma unroll
        for (int h = 0; h < 8; ++h) {
            float vv = acc[h];
#pragma unroll
            for (int o_ = 32; o_ > 0; o_ >>= 1) vv += __shfl_xor(vv, o_);
            if (lane == 0) bsm[h * 32 + rl] = vv * scale;
        }
    }
    __syncthreads();
    const vf4* bs4 = (const vf4*)bsm;          // [8][8]
    vf4* o4 = (vf4*)out_lb;
    int v = threadIdx.x & 7, sq0 = threadIdx.x >> 3;   // 64 segments per pass
#pragma unroll
    for (int it = 0; it < 32; ++it) {
        int seg = sq0 + it * 64;               // 0..2047 = h*256 + q
        int h = seg >> 8, q = seg & 255;
        vf4 val = bs4[h * 8 + v];
        __builtin_nontemporal_store(val, &o4[(((size_t)(b * 8 + h) * 256 + q) << 6) + kt * 8 + v]);
    }
}

extern "C" void kernel_launch(void* const* d_in, const int* in_sizes, int n_in,
                              void* d_out, int out_size, void* d_ws, size_t ws_size,
                              hipStream_t stream)
{
    (void)in_sizes; (void)n_in; (void)out_size; (void)ws_size;
    const float* emb_cause  = (const float*)d_in[0];
    const float* emb_action = (const float*)d_in[1];
    const float* tok_cause  = (const float*)d_in[2];
    const float* tok_effect = (const float*)d_in[3];
    const float* fuse_ln_g  = (const float*)d_in[4];
    const float* fuse_ln_b  = (const float*)d_in[5];
    const float* fuse_w1    = (const float*)d_in[6];
    const float* fuse_b1    = (const float*)d_in[7];
    const float* fuse_w2    = (const float*)d_in[8];
    const float* fuse_b2    = (const float*)d_in[9];
    const float* delta_ln_g = (const float*)d_in[10];
    const float* delta_ln_b = (const float*)d_in[11];
    const float* delta_w    = (const float*)d_in[12];
    const float* delta_b    = (const float*)d_in[13];
    const float* qg_w       = (const float*)d_in[14];
    const float* qg_b       = (const float*)d_in[15];
    const float* kg_w       = (const float*)d_in[16];
    const float* kg_b       = (const float*)d_in[17];
    const float* eff_ln_g   = (const float*)d_in[18];
    const float* eff_ln_b   = (const float*)d_in[19];
    const float* eff_w1     = (const float*)d_in[20];
    const float* eff_b1     = (const float*)d_in[21];
    const float* eff_w2     = (const float*)d_in[22];
    const float* eff_b2     = (const float*)d_in[23];
    const float* u_w        = (const float*)d_in[24];
    const float* v_w        = (const float*)d_in[25];
    const float* logit_sc   = (const float*)d_in[26];

    float* ws = (float*)d_ws;
    float* pp     = ws + 0;        // 196608
    float* wu     = ws + 196608;   // 393216
    float* stats1 = ws + 589824;   // 128
    float* stats2 = ws + 589952;   // 128
    float* gW1    = ws + 590080;   // 768
    float* bW1    = ws + 590848;   // 768
    float* dgW    = ws + 591616;   // 768
    float* dbW    = ws + 592384;   // 768
    float* egW    = ws + 593152;   // 768
    float* ebW    = ws + 593920;   // 768  (end 594688 floats = 2.4 MB)

    float* out    = (float*)d_out;
    float* out_qg = out + 0;
    float* out_kg = out + 65536;
    float* out_es = out + 131072;
    float* out_de = out + 180224;
    float* out_lb = out + 229376;
    float* out_ep = out + 33783808;

    // split-K partial buffers in the tail of logit_bias (overwritten last by k_biasbc)
    float* pbase = out_lb + 20000000;
    float* part1 = pbase;             // 12*64*768 = 589824
    float* part2 = pbase + 589824;    // 12*64*768 = 589824
    float* partA = pbase + 1179648;   //  8*64*3584 = 1835008
    float* partB = pbase + 3014656;   //  8*64*1792 = 917504 (end 3.93M < 13.3M spare)

    // K1: statless fuse1 GEMM || pool 0-383 || stats1 || colvec folds (parallelized)
    {
        G1Args A; A.ec = emb_cause; A.ea = emb_action;
        A.flg = fuse_ln_g; A.flb = fuse_ln_b; A.w1 = fuse_w1;
        A.dg = delta_ln_g; A.db = delta_ln_b; A.eg = eff_ln_g; A.eb = eff_ln_b;
        A.delta_w = delta_w; A.eff_w1 = eff_w1;
        A.tok_effect = tok_effect;
        A.part1 = part1; A.pp = pp; A.stats1 = stats1;
        A.gW1 = gW1; A.bW1 = bW1; A.dgW = dgW; A.dbW = dbW; A.egW = egW; A.ebW = ebW;
        k_g1<<<664, TPB, 0, stream>>>(A);
    }
    // K2: fuse2 GEMM (lazy LN-corrected GELU loader) || pool 384-767
    {
        G2Args A; A.part1 = part1; A.b1 = fuse_b1; A.w2 = fuse_w2;
        A.stats1 = stats1; A.gW1 = gW1; A.bW1 = bW1;
        A.tok_effect = tok_effect; A.part2 = part2; A.pp = pp;
        k_g2<<<528, TPB, 0, stream>>>(A);
    }
    // K3: batchA partials (lazy ctx, statless) || stats2
    {
        GAArgs A; A.part2 = part2; A.b2 = fuse_b2;
        A.dg = delta_ln_g; A.eg = eff_ln_g;
        A.delta_w = delta_w; A.eff_w1 = eff_w1; A.qg_w = qg_w; A.kg_w = kg_w;
        A.partA = partA; A.stats2 = stats2;
        k_gA<<<512, TPB, 0, stream>>>(A);
    }
    // K4: batchA outputs (affine-corrected) || batchB partials
    {
        MidArgs M; M.partA = partA; M.pp = pp; M.stats2 = stats2;
        M.dgW = dgW; M.dbW = dbW; M.egW = egW; M.ebW = ebW;
        M.delta_b = delta_b; M.eff_b1 = eff_b1; M.qg_b = qg_b; M.kg_b = kg_b;
        M.eff_w2 = eff_w2; M.u_w = u_w; M.partB = partB;
        M.out_de = out_de; M.out_es = out_es; M.out_qg = out_qg; M.out_kg = out_kg;
        k_mid<<<252, TPB, 0, stream>>>(M);
    }
    // K5: effect_pred epilogue || wu fold
    k_tail<<<102, TPB, 0, stream>>>(partB, eff_b2, v_w, out_ep, wu);
    // K6: fused per-(b,h,k) bias + q-broadcast
    k_biasbc<<<dim3(64, 8), 512, 0, stream>>>(tok_cause, wu, logit_sc, out_lb);
}